// Round 1
// 530.780 us; speedup vs baseline: 1.0688x; 1.0688x over previous
//
#include <hip/hip_runtime.h>

typedef unsigned int u32;
typedef unsigned long long u64;
typedef _Float16 f16;
typedef __attribute__((ext_vector_type(4))) _Float16 f16x4;
typedef __attribute__((ext_vector_type(8))) _Float16 f16x8;
typedef __attribute__((ext_vector_type(4))) float f32x4;
typedef const __attribute__((address_space(1))) void* gp_t;
typedef __attribute__((address_space(3))) void* lp_t;

#define TSEQ 2048

// monotone fp32 -> u32 map (order-preserving)
__device__ __forceinline__ u32 f2sort(float f) {
  u32 u = __float_as_uint(f);
  return u ^ ((u32)((int)u >> 31) | 0x80000000u);
}
__device__ __forceinline__ float sort2f(u32 u) {
  u ^= (u & 0x80000000u) ? 0x80000000u : 0xFFFFFFFFu;
  return __uint_as_float(u);
}

__device__ __forceinline__ void glds16(const f16* g, f16* l) {
  __builtin_amdgcn_global_load_lds((gp_t)g, (lp_t)l, 16, 0, 0);
}

__device__ __forceinline__ u32 umax2(u32 a, u32 b) { return a > b ? a : b; }

// max across each 16-lane DPP row via rotate-reduce (row_ror 8/4/2/1).
// All 16 lanes end with the row max; DPP-only, no LDS op on the chain.
__device__ __forceinline__ u32 dppmax16(u32 v) {
  u32 t;
  t = (u32)__builtin_amdgcn_update_dpp(0, (int)v, 0x128, 0xF, 0xF, true);
  v = v > t ? v : t;
  t = (u32)__builtin_amdgcn_update_dpp(0, (int)v, 0x124, 0xF, 0xF, true);
  v = v > t ? v : t;
  t = (u32)__builtin_amdgcn_update_dpp(0, (int)v, 0x122, 0xF, 0xF, true);
  v = v > t ? v : t;
  t = (u32)__builtin_amdgcn_update_dpp(0, (int)v, 0x121, 0xF, 0xF, true);
  v = v > t ? v : t;
  return v;
}
// sum across each 16-lane row via rotate-reduce, result in all 16 lanes
__device__ __forceinline__ float dppsum16(float v) {
  float t;
  t = __int_as_float(
      __builtin_amdgcn_update_dpp(0, __float_as_int(v), 0x128, 0xF, 0xF, true));
  v += t;
  t = __int_as_float(
      __builtin_amdgcn_update_dpp(0, __float_as_int(v), 0x124, 0xF, 0xF, true));
  v += t;
  t = __int_as_float(
      __builtin_amdgcn_update_dpp(0, __float_as_int(v), 0x122, 0xF, 0xF, true));
  v += t;
  t = __int_as_float(
      __builtin_amdgcn_update_dpp(0, __float_as_int(v), 0x121, 0xF, 0xF, true));
  v += t;
  return v;
}

// ---------------------------------------------------------------------------
// fp32 -> f16: x (1048576 f4), Wq (524288), Wo (262144), keys (131072).
// values stay fp32 (gathered directly). grid = 7680 blocks exactly.
// ---------------------------------------------------------------------------
__global__ __launch_bounds__(256) void cvt_all(
    const float* __restrict__ x, const float* __restrict__ wq,
    const float* __restrict__ wo, const float* __restrict__ ky,
    f16* __restrict__ xd, f16* __restrict__ wqd, f16* __restrict__ wod,
    f16* __restrict__ kyd) {
  int g = blockIdx.x * 256 + threadIdx.x;
  const float* s;
  f16* d;
  int off;
  if (g < 1048576)      { s = x;  d = xd;  off = g; }
  else if (g < 1572864) { s = wq; d = wqd; off = g - 1048576; }
  else if (g < 1835008) { s = wo; d = wod; off = g - 1572864; }
  else                  { s = ky; d = kyd; off = g - 1835008; }
  float4 v = ((const float4*)s)[off];
  f16x4 o;
  o[0] = (f16)v.x; o[1] = (f16)v.y; o[2] = (f16)v.z; o[3] = (f16)v.w;
  ((f16x4*)d)[off] = o;
}

// ---------------------------------------------------------------------------
// m97-style f16 NT GEMM: C[m,n] = sum_k A[m,k]*B[n,k] (+bias), A/B f16,
// C fp32 or f16. 128x128 tile, BK=32, global_load_lds width=16.
// ---------------------------------------------------------------------------
__global__ __launch_bounds__(256) void gemm_f16(
    const f16* __restrict__ A, int lda, const f16* __restrict__ B, int ldb,
    const float* __restrict__ bias, void* __restrict__ Cv, int ldc, int K,
    int c_f16) {
  __shared__ f16 As[128 * 32];
  __shared__ f16 Bs[128 * 32];
  const int tid = threadIdx.x;
  const int lane = tid & 63, wave = tid >> 6;
  const int m0 = blockIdx.y << 7, n0 = blockIdx.x << 7;
  const int c0 = wave * 128 + lane, c1 = c0 + 64;
  const int r0 = c0 >> 2, s0 = c0 & 3;
  const int r1 = c1 >> 2, s1 = c1 & 3;
  const f16* Ab = A + (size_t)m0 * lda;
  const f16* Bb = B + (size_t)n0 * ldb;
  const int fm = lane & 15, fq = lane >> 4, fk = fq << 3;
  const int wm = (wave >> 1) << 6, wn = (wave & 1) << 6;
  f32x4 acc[4][4] = {};
  for (int k0 = 0; k0 < K; k0 += 32) {
    __syncthreads();
    glds16(Ab + (size_t)r0 * lda + k0 + s0 * 8, As + (size_t)c0 * 8 - lane * 8);
    glds16(Ab + (size_t)r1 * lda + k0 + s1 * 8, As + (size_t)c1 * 8 - lane * 8);
    glds16(Bb + (size_t)r0 * ldb + k0 + s0 * 8, Bs + (size_t)c0 * 8 - lane * 8);
    glds16(Bb + (size_t)r1 * ldb + k0 + s1 * 8, Bs + (size_t)c1 * 8 - lane * 8);
    __syncthreads();
    f16x8 af[4], bf[4];
#pragma unroll
    for (int mi = 0; mi < 4; mi++)
      af[mi] = *(const f16x8*)&As[(wm + mi * 16 + fm) * 32 + fk];
#pragma unroll
    for (int nj = 0; nj < 4; nj++)
      bf[nj] = *(const f16x8*)&Bs[(wn + nj * 16 + fm) * 32 + fk];
#pragma unroll
    for (int mi = 0; mi < 4; mi++)
#pragma unroll
      for (int nj = 0; nj < 4; nj++)
        acc[mi][nj] = __builtin_amdgcn_mfma_f32_16x16x32_f16(
            af[mi], bf[nj], acc[mi][nj], 0, 0, 0);
  }
  if (c_f16) {
    f16* C = (f16*)Cv;
#pragma unroll
    for (int mi = 0; mi < 4; mi++)
#pragma unroll
      for (int r = 0; r < 4; r++) {
        int row = m0 + wm + mi * 16 + fq * 4 + r;
        f16* cp = C + (size_t)row * ldc + n0 + wn + fm;
#pragma unroll
        for (int nj = 0; nj < 4; nj++) cp[nj * 16] = (f16)acc[mi][nj][r];
      }
  } else {
    float* C = (float*)Cv;
    float bb[4];
#pragma unroll
    for (int nj = 0; nj < 4; nj++)
      bb[nj] = bias ? bias[n0 + wn + nj * 16 + fm] : 0.f;
#pragma unroll
    for (int mi = 0; mi < 4; mi++)
#pragma unroll
      for (int r = 0; r < 4; r++) {
        int row = m0 + wm + mi * 16 + fq * 4 + r;
        float* cp = C + (size_t)row * ldc + n0 + wn + fm;
#pragma unroll
        for (int nj = 0; nj < 4; nj++) cp[nj * 16] = acc[mi][nj][r] + bb[nj];
      }
  }
}

// ---------------------------------------------------------------------------
// Fused dots + stage-1 top-32. blockIdx.x = z = h*2+p (fastest, Q reuse),
// blockIdx.y = m-tile. Wave computes 16 rows x 256 cols; selection via DPP
// rotate-reduce max; key low byte = (slot<<4)|lane (self-owning).
// ---------------------------------------------------------------------------
__global__ __launch_bounds__(256) void dots_topk1(
    const f16* __restrict__ Q,      // (4096, 2048)
    const f16* __restrict__ keysf,  // (8,256,2,128)
    float* __restrict__ s1s, int* __restrict__ s1i) {
  __shared__ f16 As[64 * 32];
  __shared__ f16 Bs[256 * 32];
  const int tid = threadIdx.x;
  const int lane = tid & 63, wave = tid >> 6;
  const int z = blockIdx.x;  // h*2+p
  const int h = z >> 1, p = z & 1;
  const int m0 = blockIdx.y << 6;
  const f16* Aq = Q + (size_t)m0 * 2048 + p * 1024 + h * 128;
  const f16* Bk = keysf + ((size_t)h * 512 + p) * 128;  // row stride 256 f16
  const int cA = wave * 64 + lane;
  const int rA = cA >> 2, sA = cA & 3;
  const int fm = lane & 15, fq = lane >> 4, fk = fq << 3;
  f32x4 acc[16] = {};
  for (int k0 = 0; k0 < 128; k0 += 32) {
    __syncthreads();
    glds16(Aq + (size_t)rA * 2048 + k0 + sA * 8, As + (size_t)cA * 8 - lane * 8);
#pragma unroll
    for (int c = 0; c < 4; c++) {
      int cB = (wave * 4 + c) * 64 + lane;
      int rB = cB >> 2, sB = cB & 3;
      glds16(Bk + (size_t)rB * 256 + k0 + sB * 8,
             Bs + (size_t)cB * 8 - lane * 8);
    }
    __syncthreads();
    f16x8 af = *(const f16x8*)&As[(wave * 16 + fm) * 32 + fk];
#pragma unroll
    for (int j = 0; j < 16; j++) {
      f16x8 bf = *(const f16x8*)&Bs[(j * 16 + fm) * 32 + fk];
      acc[j] = __builtin_amdgcn_mfma_f32_16x16x32_f16(af, bf, acc[j], 0, 0, 0);
    }
  }
  // top-32 per row; quad fq handles rows m0 + wave*16 + fq*4 + r.
  // score row element n = j*16 + fm lives in acc[j][r] of lane (fq*16+fm).
  for (int r = 0; r < 4; r++) {
    u32 key[16];
#pragma unroll
    for (int j = 0; j < 16; j++)
      key[j] = (f2sort(acc[j][r]) & ~0xFFu) | (u32)((j << 4) | fm);
    u32 g0 = 0, g1 = 0;
    for (int it = 0; it < 32; it++) {
      // depth-4 tree max over the 16 local keys
      u32 t0 = umax2(key[0], key[1]), t1 = umax2(key[2], key[3]);
      u32 t2 = umax2(key[4], key[5]), t3 = umax2(key[6], key[7]);
      u32 t4 = umax2(key[8], key[9]), t5 = umax2(key[10], key[11]);
      u32 t6 = umax2(key[12], key[13]), t7 = umax2(key[14], key[15]);
      t0 = umax2(t0, t1); t2 = umax2(t2, t3);
      t4 = umax2(t4, t5); t6 = umax2(t6, t7);
      u32 lm = umax2(umax2(t0, t2), umax2(t4, t6));
      u32 gm = dppmax16(lm);
#pragma unroll
      for (int j = 0; j < 16; j++) key[j] = (key[j] == gm) ? 0u : key[j];
      bool sel = (fm == (it & 15));
      if (it < 16) g0 = sel ? gm : g0;
      else         g1 = sel ? gm : g1;
    }
    int m = m0 + wave * 16 + (fq << 2) + r;
    int b = m >> 11, t = m & 2047;
    size_t orow = ((((size_t)(b * 8 + h)) * TSEQ + t) * 2 + p) * 32;
    s1s[orow + fm] = sort2f(g0 & ~0xFFu);
    s1s[orow + fm + 16] = sort2f(g1 & ~0xFFu);
    s1i[orow + fm] = (int)(g0 & 0xFFu);       // n = (slot<<4)|lane
    s1i[orow + fm + 16] = (int)(g1 & 0xFFu);
  }
}

// ---------------------------------------------------------------------------
// Stage-2: combine halves, top-32 of 32x32 sum grid via dominance frontier
// ((i+1)(j+1)<=32 -> 119 candidates), DPP selection, softmax, fp32 value
// gather straight from the input table (L3-resident), weighted sum -> f16.
// ---------------------------------------------------------------------------
__global__ __launch_bounds__(256) void topk2_gather(
    const float* __restrict__ s1s, const int* __restrict__ s1i,
    const float* __restrict__ valf, f16* __restrict__ headout) {
  __shared__ unsigned short cand[128];  // (i<<5)|j, 0xFFFF = pad
  __shared__ float s0sh[16][32];
  __shared__ float s1sh[16][32];
  __shared__ int i0sh[16][32];
  __shared__ int i1sh[16][32];
  __shared__ int vtab[16][32];
  __shared__ float wtab[16][32];
  const int tid = threadIdx.x;
  if (tid < 128) {
    int c = tid;
    unsigned short enc = 0xFFFF;
    if (c < 119) {
      int rem = c, i = 0;
      for (i = 0; i < 32; i++) {
        int cnt = 32 / (i + 1);
        if (rem < cnt) break;
        rem -= cnt;
      }
      enc = (unsigned short)((i << 5) | rem);
    }
    cand[tid] = enc;
  }
  const int rloc = tid >> 4;
  const int l = tid & 15;
  const int row = blockIdx.x * 16 + rloc;  // (b,h,t)
  const int b = row >> 14;
  const int h = (row >> 11) & 7;
  const int t = row & 2047;
  const int tt = t >> 1, p = t & 1;
  size_t rbase = (size_t)(b * 8 + h) * TSEQ;
  size_t base0 = ((rbase + tt) * 2 + p) * 32;
  size_t base1 = ((rbase + tt + 1024) * 2 + p) * 32;
  s0sh[rloc][l] = s1s[base0 + l];
  s0sh[rloc][l + 16] = s1s[base0 + l + 16];
  s1sh[rloc][l] = s1s[base1 + l];
  s1sh[rloc][l + 16] = s1s[base1 + l + 16];
  i0sh[rloc][l] = s1i[base0 + l];
  i0sh[rloc][l + 16] = s1i[base0 + l + 16];
  i1sh[rloc][l] = s1i[base1 + l];
  i1sh[rloc][l + 16] = s1i[base1 + l + 16];
  __syncthreads();
  u32 key[8];
#pragma unroll
  for (int s = 0; s < 8; s++) {
    int c = l + 16 * s;  // == (s<<4)|l
    unsigned short e = cand[c];
    u32 kk = 0u;
    if (e != 0xFFFF) {
      float v = s0sh[rloc][e >> 5] + s1sh[rloc][e & 31];
      kk = (f2sort(v) & ~0xFFu) | (u32)c;
    }
    key[s] = kk;
  }
  u32 g0 = 0, g1 = 0;
  for (int it = 0; it < 32; it++) {
    // depth-3 tree max over the 8 local keys
    u32 t0 = umax2(key[0], key[1]), t1 = umax2(key[2], key[3]);
    u32 t2 = umax2(key[4], key[5]), t3 = umax2(key[6], key[7]);
    u32 lm = umax2(umax2(t0, t1), umax2(t2, t3));
    u32 gm = dppmax16(lm);
#pragma unroll
    for (int s = 0; s < 8; s++) key[s] = (key[s] == gm) ? 0u : key[s];
    bool sel = (l == (it & 15));
    if (it < 16) g0 = sel ? gm : g0;
    else         g1 = sel ? gm : g1;
  }
  // decode winners (lane l holds winners l and l+16, descending order)
  float sc0 = sort2f(g0 & ~0xFFu);
  float sc1 = sort2f(g1 & ~0xFFu);
  unsigned short e0c = cand[g0 & 0xFFu];
  unsigned short e1c = cand[g1 & 0xFFu];
  int vidx0 = i0sh[rloc][e0c >> 5] * 256 + i1sh[rloc][e0c & 31];
  int vidx1 = i0sh[rloc][e1c >> 5] * 256 + i1sh[rloc][e1c & 31];
  // softmax: winner 0 (group lane 0) is the max
  float mx = __int_as_float(
      __builtin_amdgcn_ds_swizzle(__float_as_int(sc0), 0x010));
  float e0 = __expf(sc0 - mx);
  float e1 = __expf(sc1 - mx);
  float inv = 1.0f / dppsum16(e0 + e1);
  vtab[rloc][l] = vidx0;
  vtab[rloc][l + 16] = vidx1;
  wtab[rloc][l] = e0 * inv;
  wtab[rloc][l + 16] = e1 * inv;
  // gather: 128 fp32 per value row; lane reads 8 floats (2x16 B) -> 512 B/row
  const float* vb = valf + (((size_t)h) << 23) + (size_t)l * 8;
  float accf[8] = {};
#pragma unroll 8
  for (int k = 0; k < 32; k++) {
    int vi = vtab[rloc][k];      // LDS broadcast (same wave, no barrier)
    float wk = wtab[rloc][k];
    const float4* vp = (const float4*)(vb + (size_t)vi * 128);
    float4 v0 = vp[0];
    float4 v1 = vp[1];
    accf[0] += wk * v0.x; accf[1] += wk * v0.y;
    accf[2] += wk * v0.z; accf[3] += wk * v0.w;
    accf[4] += wk * v1.x; accf[5] += wk * v1.y;
    accf[6] += wk * v1.z; accf[7] += wk * v1.w;
  }
  f16x8 o;
#pragma unroll
  for (int j = 0; j < 8; j++) o[j] = (f16)accf[j];
  f16* op = headout + (size_t)(b * TSEQ + t) * 1024 + h * 128 + l * 8;
  *(f16x8*)op = o;
}

// ---------------------------------------------------------------------------
extern "C" void kernel_launch(void* const* d_in, const int* in_sizes, int n_in,
                              void* d_out, int out_size, void* d_ws,
                              size_t ws_size, hipStream_t stream) {
  const float* x    = (const float*)d_in[0];  // (2,2048,1024)
  const float* Wq   = (const float*)d_in[1];  // (2048,1024)
  const float* keys = (const float*)d_in[2];  // (8,256,2,128)
  const float* vals = (const float*)d_in[3];  // (8,65536,128) fp32, gathered
  const float* Wo   = (const float*)d_in[4];  // (1024,1024)
  const float* bo   = (const float*)d_in[5];  // (1024,)
  float* out = (float*)d_out;                 // (2,2048,1024) fp32
  char* ws = (char*)d_ws;
  f16*   xf   = (f16*)(ws);                         // 8 MB
  f16*   wqf  = (f16*)(ws + (size_t)(8u << 20));    // 4 MB
  f16*   wof  = (f16*)(ws + (size_t)(12u << 20));   // 2 MB
  f16*   kyf  = (f16*)(ws + (size_t)(14u << 20));   // 1 MB
  f16*   Qf   = (f16*)(ws + (size_t)(16u << 20));   // 16 MB (4096x2048)
  float* s1s  = (float*)(ws + (size_t)(32u << 20)); // 8 MB
  int*   s1i  = (int*)(ws + (size_t)(40u << 20));   // 8 MB
  f16*   hof  = (f16*)(ws + (size_t)(48u << 20));   // 8 MB (4096x1024)

  // 0) fp32 -> f16 for x, Wq, Wo, keys (values stay fp32)
  cvt_all<<<dim3(7680), 256, 0, stream>>>(x, Wq, Wo, keys, xf, wqf, wof, kyf);
  // 1) Q = x @ Wq^T  (M=4096,N=2048,K=1024), f16 out
  gemm_f16<<<dim3(16, 32), 256, 0, stream>>>(xf, 1024, wqf, 1024, nullptr, Qf,
                                             2048, 1024, 1);
  // 2) dots + stage-1 top-32 fused (per (h,p): M=4096,N=256,K=128)
  dots_topk1<<<dim3(16, 64), 256, 0, stream>>>(Qf, kyf, s1s, s1i);
  // 3) stage-2 top-32 + softmax + fp32 gather -> headout f16
  topk2_gather<<<dim3(32768 / 16), 256, 0, stream>>>(s1s, s1i, vals, hof);
  // 4) out = headout @ Wo^T + bo  (M=4096,N=1024,K=1024), fp32 out
  gemm_f16<<<dim3(8, 32), 256, 0, stream>>>(hof, 1024, wof, 1024, bo, out,
                                            1024, 1024, 0);
}